// Round 6
// baseline (139.648 us; speedup 1.0000x reference)
//
#include <hip/hip_runtime.h>
#include <math.h>

#define Bz 2
#define Az 2
#define Cz 10
#define HWz 1024
#define Nz 2048              // HWz * Az
#define ACHW (Az*Cz*HWz)     // 20480
#define NBBOX (Bz*Az*7*HWz)  // 28672
#define NPP   (Bz*Cz*3*HWz)  // 61440
#define EPSf 1e-6f
#define LOG2E 1.4426950408889634f
#define NACC (Bz*16*2560)    // accumulator floats = 81920

#if __has_builtin(__builtin_amdgcn_exp2f)
#define EXP2F(x) __builtin_amdgcn_exp2f(x)
#else
#define EXP2F(x) exp2f(x)
#endif
#if __has_builtin(__builtin_amdgcn_rcpf)
#define RCPF(x) __builtin_amdgcn_rcpf(x)
#else
#define RCPF(x) (1.0f/(x))
#endif

static __device__ __forceinline__ unsigned short f2bf(float x) {
    unsigned u = __builtin_bit_cast(unsigned, x);
    unsigned r = (u + 0x7fffu + ((u >> 16) & 1u)) >> 16;
    return (unsigned short)r;
}

static __device__ __forceinline__ float iou_e(float nx1,float ny1,float nx2,float ny2,float ar,
                                              float mx1,float my1,float mx2,float my2,float am) {
    float xx1 = fmaxf(nx1, mx1), yy1 = fmaxf(ny1, my1);
    float xx2 = fminf(nx2, mx2), yy2 = fminf(ny2, my2);
    float iw = fmaxf(xx2 - xx1, 0.f), ih = fmaxf(yy2 - yy1, 0.f);
    float inter = iw * ih;
    float uni = fmaxf(ar + am - inter, EPSf);
    return EXP2F(inter * LOG2E * RCPF(uni));   // exp2(iou*log2e)
}

// ws: LT float2[B*N] | RB float2[B*N] | GPQ2 uint2[B][HW][C] = {p1*log2e f32, bf16(q0)|bf16(q1)<<16}
//     | A float[B*16*2560] atomic accumulator (zeroed by k_pre)

// ---- fused prep: passthrough copies + BEV + per-(b,c) softmax + zero A
__global__ __launch_bounds__(256) void k_pre(const float* __restrict__ scores,
                                             const float* __restrict__ bbox,
                                             const float* __restrict__ pp,
                                             const float* __restrict__ dec,
                                             float* __restrict__ out,
                                             float2* __restrict__ LT,
                                             float2* __restrict__ RB,
                                             uint2* __restrict__ GPQ2,
                                             float* __restrict__ A) {
    int blk = blockIdx.x;
    int tid = threadIdx.x;
    __shared__ float red[256];

    if (blk < 240) {                    // copies
        int i = blk * 256 + tid;
        if (i < NBBOX) out[Bz*ACHW + i] = bbox[i];
        if (i < NPP)   out[Bz*ACHW + NBBOX + i] = pp[i];
        return;
    }
    if (blk < 256) {                    // BEV (4096 boxes)
        int i = (blk - 240) * 256 + tid;
        const float* d = dec + i*7;
        float x = d[0], y = d[1], dx = d[3], dy = d[4], yaw = d[6];
        const float PI = 3.14159265358979323846f;
        float normed = fabsf(yaw - floorf(yaw/PI + 0.5f) * PI);
        bool swp = normed > PI * 0.25f;
        float w = swp ? dy : dx;
        float h = swp ? dx : dy;
        LT[i] = make_float2(x - 0.5f*w, y - 0.5f*h);
        RB[i] = make_float2(x + 0.5f*w, y + 0.5f*h);
        return;
    }
    if (blk >= 276) {                   // zero accumulator A (80 blocks x 1024 floats)
        float4* A4 = (float4*)A;
        A4[(blk - 276) * 256 + tid] = make_float4(0.f, 0.f, 0.f, 0.f);
        return;
    }
    // softmax over n for (b,c)
    int bc = blk - 256;
    int b = bc / Cz, c = bc % Cz;
    const float* sbase = scores + b*ACHW;
    float vals[Nz/256];
    float mx = -INFINITY;
    #pragma unroll
    for (int j = 0; j < Nz/256; j++) {
        int n = tid + j*256;
        int a = n & 1, hw = n >> 1;
        float v = sbase[(a*Cz + c)*HWz + hw];
        vals[j] = v;
        mx = fmaxf(mx, v);
    }
    red[tid] = mx; __syncthreads();
    for (int s = 128; s > 0; s >>= 1) {
        if (tid < s) red[tid] = fmaxf(red[tid], red[tid+s]);
        __syncthreads();
    }
    mx = red[0]; __syncthreads();
    float sum = 0.f;
    #pragma unroll
    for (int j = 0; j < Nz/256; j++) {
        vals[j] = EXP2F((vals[j] - mx) * LOG2E);
        sum += vals[j];
    }
    red[tid] = sum; __syncthreads();
    for (int s = 128; s > 0; s >>= 1) {
        if (tid < s) red[tid] += red[tid+s];
        __syncthreads();
    }
    float inv = 1.f / red[0];
    const float* p1base = pp + b*Cz*3*HWz + (c*3 + 1)*HWz;
    uint2* gp = GPQ2 + (size_t)b*HWz*Cz;
    #pragma unroll
    for (int j = 0; j < Nz/256; j++) {
        __syncthreads();
        red[tid] = vals[j] * inv;
        __syncthreads();
        if (tid < 128) {
            int hm = (j << 7) + tid;
            float q0 = red[2*tid], q1 = red[2*tid + 1];
            unsigned qq = (unsigned)f2bf(q0) | ((unsigned)f2bf(q1) << 16);
            float p1 = p1base[hm] * LOG2E;
            gp[hm*Cz + c] = make_uint2(__builtin_bit_cast(unsigned, p1), qq);
        }
    }
}

// ---- main: 1024 blocks (b, g in 16, sp in 32). Slice = 32 hm-pairs staged in LDS;
// lane = hn-pair (n-side in regs), wave takes 8 pairs. In-block LDS-atomic reduce,
// then 2560 global atomicAdds into A.
__global__ __launch_bounds__(256, 4) void k_main(const float4* __restrict__ LT4,
                                                 const float4* __restrict__ RB4,
                                                 const uint2* __restrict__ GPQ2,
                                                 const float* __restrict__ pp,
                                                 float* __restrict__ A) {
    __shared__ __align__(16) float4 SLT[32];
    __shared__ __align__(16) float4 SRB[32];
    __shared__ __align__(16) uint2  SPQ[320];    // [pair][c]
    __shared__ float RED[2560];                  // [v][lane], v in [0,40)

    int tid = threadIdx.x;
    int wave = tid >> 6, lane = tid & 63;
    int bid = blockIdx.x;
    int b = bid >> 9;
    int r = bid & 511;
    int g = r >> 5, sp = r & 31;
    int hbase = sp << 5;                          // hm-pair base

    const float4* LTb = LT4 + (b << 10);
    const float4* RBb = RB4 + (b << 10);
    const uint2*  Qb  = GPQ2 + (size_t)b*HWz*Cz + (size_t)hbase*Cz;

    // stage m-side slice
    if (tid < 32)       SLT[tid] = LTb[hbase + tid];
    else if (tid < 64)  SRB[tid - 32] = RBb[hbase + tid - 32];
    for (int i = tid; i < 320; i += 256) SPQ[i] = Qb[i];
    // zero reduction buffer
    #pragma unroll
    for (int k = 0; k < 10; k++) RED[tid + (k << 8)] = 0.f;

    // n-side (per lane): boxes + p0
    int hn = (g << 6) + lane;
    float4 bx = LTb[hn], by = RBb[hn];
    float ar0 = (by.x - bx.x) * (by.y - bx.y);
    float ar1 = (by.z - bx.z) * (by.w - bx.w);
    float p0[Cz];
    const float* p0base = pp + b*(Cz*3*HWz) + hn;
    #pragma unroll
    for (int c = 0; c < Cz; c++) p0[c] = p0base[c * 3 * HWz];

    float l0[Cz], l1[Cz], a0[Cz], a1[Cz];
    #pragma unroll
    for (int c = 0; c < Cz; c++) { l0[c]=0.f; l1[c]=0.f; a0[c]=0.f; a1[c]=0.f; }

    __syncthreads();

    int j = wave << 3;
    float4 bl = SLT[j], br = SRB[j];
    #pragma unroll 2
    for (int i = 0; i < 8; i++) {
        // issue pq-row loads early (consumed after the iou math)
        const uint4* row4 = (const uint4*)(SPQ + j*Cz);
        uint4 q01 = row4[0], q23 = row4[1], q45 = row4[2], q67 = row4[3], q89 = row4[4];
        float4 nbl, nbr;
        if (i < 7) { nbl = SLT[j+1]; nbr = SRB[j+1]; }

        float am0 = (br.x - bl.x) * (br.y - bl.y);
        float am1 = (br.z - bl.z) * (br.w - bl.w);
        float E00 = iou_e(bx.x,bx.y,by.x,by.y,ar0, bl.x,bl.y,br.x,br.y,am0);
        float E01 = iou_e(bx.x,bx.y,by.x,by.y,ar0, bl.z,bl.w,br.z,br.w,am1);
        float E10 = iou_e(bx.z,bx.w,by.z,by.w,ar1, bl.x,bl.y,br.x,br.y,am0);
        float E11 = iou_e(bx.z,bx.w,by.z,by.w,ar1, bl.z,bl.w,br.z,br.w,am1);
        float S0 = E00 + E01, S1 = E10 + E11;

        unsigned pqx[Cz] = {q01.x, q01.z, q23.x, q23.z, q45.x, q45.z, q67.x, q67.z, q89.x, q89.z};
        unsigned pqy[Cz] = {q01.y, q01.w, q23.y, q23.w, q45.y, q45.w, q67.y, q67.w, q89.y, q89.w};
        #pragma unroll
        for (int c = 0; c < Cz; c++) {
            float p1 = __builtin_bit_cast(float, pqx[c]);
            float q0 = __builtin_bit_cast(float, pqy[c] << 16);
            float q1 = __builtin_bit_cast(float, pqy[c] & 0xffff0000u);
            float F = EXP2F(p0[c] * p1);
            l0[c] = fmaf(F, S0, l0[c]);
            l1[c] = fmaf(F, S1, l1[c]);
            float t0 = fmaf(E01, q1, E00 * q0);
            float t1 = fmaf(E11, q1, E10 * q0);
            a0[c] = fmaf(F, t0, a0[c]);
            a1[c] = fmaf(F, t1, a1[c]);
        }
        bl = nbl; br = nbr; j++;
    }

    // in-block reduce: RED[v*64+lane] += (conflict-free layout, atomics across waves)
    __syncthreads();
    #pragma unroll
    for (int c = 0; c < Cz; c++) {
        atomicAdd(&RED[(c      ) * 64 + lane], l0[c]);
        atomicAdd(&RED[(10 + c) * 64 + lane], l1[c]);
        atomicAdd(&RED[(20 + c) * 64 + lane], a0[c]);
        atomicAdd(&RED[(30 + c) * 64 + lane], a1[c]);
    }
    __syncthreads();

    float* Ab = A + (size_t)(b*16 + g) * 2560;
    #pragma unroll
    for (int k = 0; k < 10; k++) {
        int u = tid + (k << 8);
        atomicAdd(Ab + u, RED[u]);
    }
}

// ---- finalize: out = a / l from accumulator
__global__ __launch_bounds__(256) void k_fin(const float* __restrict__ A,
                                             float* __restrict__ out) {
    int bg = blockIdx.x;                 // b*16+g in [0,32)
    int b = bg >> 4, g = bg & 15;
    const float* Ab = A + (size_t)bg * 2560;
    int tid = threadIdx.x;
    #pragma unroll
    for (int k = 0; k < 5; k++) {
        int pos = tid + (k << 8);        // [0,1280): v2*64+lane
        int v2 = pos >> 6, ln = pos & 63;
        float l = Ab[pos];
        float a = Ab[1280 + pos];
        int row = v2 / 10, c = v2 % 10;
        out[b*ACHW + (row*Cz + c)*HWz + (g << 6) + ln] = a * RCPF(l);
    }
}

extern "C" void kernel_launch(void* const* d_in, const int* in_sizes, int n_in,
                              void* d_out, int out_size, void* d_ws, size_t ws_size,
                              hipStream_t stream) {
    const float* scores = (const float*)d_in[0];
    const float* bbox   = (const float*)d_in[1];
    const float* pp     = (const float*)d_in[2];
    const float* dec    = (const float*)d_in[3];
    float* out = (float*)d_out;

    float2* LT = (float2*)d_ws;
    float2* RB = LT + (size_t)Bz*Nz;
    uint2*  PQ = (uint2*)(RB + (size_t)Bz*Nz);
    float*  A  = (float*)(PQ + (size_t)Bz*HWz*Cz);

    hipLaunchKernelGGL(k_pre,  dim3(356),  dim3(256), 0, stream,
                       scores, bbox, pp, dec, out, LT, RB, PQ, A);
    hipLaunchKernelGGL(k_main, dim3(1024), dim3(256), 0, stream,
                       (const float4*)LT, (const float4*)RB, PQ, pp, A);
    hipLaunchKernelGGL(k_fin,  dim3(32),   dim3(256), 0, stream, A, out);
}

// Round 7
// 98.994 us; speedup vs baseline: 1.4107x; 1.4107x over previous
//
#include <hip/hip_runtime.h>
#include <math.h>

#define Bz 2
#define Az 2
#define Cz 10
#define HWz 1024
#define Nz 2048              // HWz * Az
#define ACHW (Az*Cz*HWz)     // 20480
#define NBBOX (Bz*Az*7*HWz)  // 28672
#define NPP   (Bz*Cz*3*HWz)  // 61440
#define EPSf 1e-6f
#define LOG2E 1.4426950408889634f

#if __has_builtin(__builtin_amdgcn_exp2f)
#define EXP2F(x) __builtin_amdgcn_exp2f(x)
#else
#define EXP2F(x) exp2f(x)
#endif
#if __has_builtin(__builtin_amdgcn_rcpf)
#define RCPF(x) __builtin_amdgcn_rcpf(x)
#else
#define RCPF(x) (1.0f/(x))
#endif

static __device__ __forceinline__ float iou_e(float nx1,float ny1,float nx2,float ny2,float ar,
                                              float mx1,float my1,float mx2,float my2,float am) {
    float xx1 = fmaxf(nx1, mx1), yy1 = fmaxf(ny1, my1);
    float xx2 = fminf(nx2, mx2), yy2 = fminf(ny2, my2);
    float iw = fmaxf(xx2 - xx1, 0.f), ih = fmaxf(yy2 - yy1, 0.f);
    float inter = iw * ih;
    float uni = fmaxf(ar + am - inter, EPSf);
    return EXP2F(inter * LOG2E * RCPF(uni));   // exp2(iou*log2e)
}

// ws: LT float2[B*N] | RB float2[B*N] | GPQ4 float4[B][HW][C] = {p1*log2e, q0, q1, 0}
//     | P float[1024][2560] partials

// ---- fused prep: passthrough copies + BEV + per-(b,c) softmax
__global__ __launch_bounds__(256) void k_pre(const float* __restrict__ scores,
                                             const float* __restrict__ bbox,
                                             const float* __restrict__ pp,
                                             const float* __restrict__ dec,
                                             float* __restrict__ out,
                                             float2* __restrict__ LT,
                                             float2* __restrict__ RB,
                                             float4* __restrict__ GPQ4) {
    int blk = blockIdx.x;
    int tid = threadIdx.x;
    __shared__ float red[256];

    if (blk < 240) {                    // copies
        int i = blk * 256 + tid;
        if (i < NBBOX) out[Bz*ACHW + i] = bbox[i];
        if (i < NPP)   out[Bz*ACHW + NBBOX + i] = pp[i];
        return;
    }
    if (blk < 256) {                    // BEV (4096 boxes)
        int i = (blk - 240) * 256 + tid;
        const float* d = dec + i*7;
        float x = d[0], y = d[1], dx = d[3], dy = d[4], yaw = d[6];
        const float PI = 3.14159265358979323846f;
        float normed = fabsf(yaw - floorf(yaw/PI + 0.5f) * PI);
        bool swp = normed > PI * 0.25f;
        float w = swp ? dy : dx;
        float h = swp ? dx : dy;
        LT[i] = make_float2(x - 0.5f*w, y - 0.5f*h);
        RB[i] = make_float2(x + 0.5f*w, y + 0.5f*h);
        return;
    }
    // softmax over n for (b,c)
    int bc = blk - 256;
    int b = bc / Cz, c = bc % Cz;
    const float* sbase = scores + b*ACHW;
    float vals[Nz/256];
    float mx = -INFINITY;
    #pragma unroll
    for (int j = 0; j < Nz/256; j++) {
        int n = tid + j*256;
        int a = n & 1, hw = n >> 1;
        float v = sbase[(a*Cz + c)*HWz + hw];
        vals[j] = v;
        mx = fmaxf(mx, v);
    }
    red[tid] = mx; __syncthreads();
    for (int s = 128; s > 0; s >>= 1) {
        if (tid < s) red[tid] = fmaxf(red[tid], red[tid+s]);
        __syncthreads();
    }
    mx = red[0]; __syncthreads();
    float sum = 0.f;
    #pragma unroll
    for (int j = 0; j < Nz/256; j++) {
        vals[j] = EXP2F((vals[j] - mx) * LOG2E);
        sum += vals[j];
    }
    red[tid] = sum; __syncthreads();
    for (int s = 128; s > 0; s >>= 1) {
        if (tid < s) red[tid] += red[tid+s];
        __syncthreads();
    }
    float inv = 1.f / red[0];
    const float* p1base = pp + b*Cz*3*HWz + (c*3 + 1)*HWz;
    float4* gp = GPQ4 + (size_t)b*HWz*Cz;
    #pragma unroll
    for (int j = 0; j < Nz/256; j++) {
        __syncthreads();
        red[tid] = vals[j] * inv;
        __syncthreads();
        if (tid < 128) {
            int hm = (j << 7) + tid;
            float q0 = red[2*tid], q1 = red[2*tid + 1];
            float p1 = p1base[hm] * LOG2E;
            gp[hm*Cz + c] = make_float4(p1, q0, q1, 0.f);
        }
    }
}

// ---- main: 1024 blocks (b, g in 16, sp in 32). Slice = 32 hm-pairs in LDS;
// lane = hn-pair (n-side in regs), wave takes 8 pairs. Cross-wave reduce via
// overlaid 40KB RED buffer, regular coalesced partial writes (NO atomics).
__global__ __launch_bounds__(256, 4) void k_main(const float4* __restrict__ LT4,
                                                 const float4* __restrict__ RB4,
                                                 const float4* __restrict__ GPQ4,
                                                 const float* __restrict__ pp,
                                                 float* __restrict__ P) {
    __shared__ __align__(16) char smem[40960];
    float4* SLT  = (float4*)smem;                 // [32]
    float4* SRB  = SLT + 32;                      // [32]
    float4* SPQ4 = SRB + 32;                      // [320] {p1L2,q0,q1,-}
    float*  RED  = (float*)smem;                  // [40][4][64] overlay (used after loop)

    int tid = threadIdx.x;
    int wave = tid >> 6, lane = tid & 63;
    int bid = blockIdx.x;
    int b = bid >> 9;
    int r = bid & 511;
    int g = r >> 5, sp = r & 31;
    int hbase = sp << 5;                          // hm-pair base

    const float4* LTb = LT4 + (b << 10);
    const float4* RBb = RB4 + (b << 10);
    const float4* Qb  = GPQ4 + (size_t)b*HWz*Cz + (size_t)hbase*Cz;

    // stage m-side slice
    if (tid < 32)       SLT[tid] = LTb[hbase + tid];
    else if (tid < 64)  SRB[tid - 32] = RBb[hbase + tid - 32];
    for (int i = tid; i < 320; i += 256) SPQ4[i] = Qb[i];

    // n-side (per lane): boxes + p0
    int hn = (g << 6) + lane;
    float4 bx = LTb[hn], by = RBb[hn];
    float ar0 = (by.x - bx.x) * (by.y - bx.y);
    float ar1 = (by.z - bx.z) * (by.w - bx.w);
    float p0[Cz];
    const float* p0base = pp + b*(Cz*3*HWz) + hn;
    #pragma unroll
    for (int c = 0; c < Cz; c++) p0[c] = p0base[c * 3 * HWz];

    float l0[Cz], l1[Cz], a0[Cz], a1[Cz];
    #pragma unroll
    for (int c = 0; c < Cz; c++) { l0[c]=0.f; l1[c]=0.f; a0[c]=0.f; a1[c]=0.f; }

    __syncthreads();

    int j = wave << 3;
    #pragma unroll 2
    for (int i = 0; i < 8; i++, j++) {
        float4 bl = SLT[j];
        float4 br = SRB[j];
        float am0 = (br.x - bl.x) * (br.y - bl.y);
        float am1 = (br.z - bl.z) * (br.w - bl.w);
        float E00 = iou_e(bx.x,bx.y,by.x,by.y,ar0, bl.x,bl.y,br.x,br.y,am0);
        float E01 = iou_e(bx.x,bx.y,by.x,by.y,ar0, bl.z,bl.w,br.z,br.w,am1);
        float E10 = iou_e(bx.z,bx.w,by.z,by.w,ar1, bl.x,bl.y,br.x,br.y,am0);
        float E11 = iou_e(bx.z,bx.w,by.z,by.w,ar1, bl.z,bl.w,br.z,br.w,am1);
        float S0 = E00 + E01, S1 = E10 + E11;
        const float4* pqrow = SPQ4 + j*Cz;
        #pragma unroll
        for (int c = 0; c < Cz; c++) {
            float4 pq = pqrow[c];              // broadcast ds_read_b128
            float F = EXP2F(p0[c] * pq.x);
            l0[c] = fmaf(F, S0, l0[c]);
            l1[c] = fmaf(F, S1, l1[c]);
            float t0 = fmaf(E01, pq.z, E00 * pq.y);
            float t1 = fmaf(E11, pq.z, E10 * pq.y);
            a0[c] = fmaf(F, t0, a0[c]);
            a1[c] = fmaf(F, t1, a1[c]);
        }
    }

    __syncthreads();                    // staged data no longer needed
    // RED[v*256 + wave*64 + lane], v = {l0:c, l1:10+c, a0:20+c, a1:30+c}
    {
        float* rw = RED + (wave << 6) + lane;
        #pragma unroll
        for (int c = 0; c < Cz; c++) {
            rw[(c      ) << 8] = l0[c];
            rw[(10 + c) << 8] = l1[c];
            rw[(20 + c) << 8] = a0[c];
            rw[(30 + c) << 8] = a1[c];
        }
    }
    __syncthreads();

    // sum 4 waves, coalesced write: P[bid*2560 + tid + 256*k], v = (tid>>6) + 4k
    float* Pb = P + (size_t)bid * 2560;
    int vg = tid >> 6, ln = tid & 63;
    #pragma unroll
    for (int k = 0; k < 10; k++) {
        int v = vg + (k << 2);
        const float* rr = RED + (v << 8) + ln;
        Pb[tid + (k << 8)] = rr[0] + rr[64] + rr[128] + rr[192];
    }
}

// ---- reduce over 32 hm-slices and finalize; 160 blocks, 1 position/thread
__global__ __launch_bounds__(256) void k_red(const float* __restrict__ P,
                                             float* __restrict__ out) {
    int bid = blockIdx.x;                // bg*5 + f
    int bg = bid / 5, f = bid % 5;
    int b = bg >> 4, g = bg & 15;
    const float* Pb = P + (size_t)(b*512 + g*32) * 2560;
    int pos = f*256 + threadIdx.x;       // [0,1280): v2*64+ln
    float l = 0.f, a = 0.f;
    #pragma unroll
    for (int sp = 0; sp < 32; sp++) {
        const float* q = Pb + (size_t)sp*2560;
        l += q[pos];
        a += q[1280 + pos];
    }
    int v2 = pos >> 6, ln = pos & 63;
    int row = v2 / 10, c = v2 % 10;
    out[b*ACHW + (row*Cz + c)*HWz + (g << 6) + ln] = a * RCPF(l);
}

extern "C" void kernel_launch(void* const* d_in, const int* in_sizes, int n_in,
                              void* d_out, int out_size, void* d_ws, size_t ws_size,
                              hipStream_t stream) {
    const float* scores = (const float*)d_in[0];
    const float* bbox   = (const float*)d_in[1];
    const float* pp     = (const float*)d_in[2];
    const float* dec    = (const float*)d_in[3];
    float* out = (float*)d_out;

    float2* LT = (float2*)d_ws;
    float2* RB = LT + (size_t)Bz*Nz;
    float4* PQ = (float4*)(RB + (size_t)Bz*Nz);
    float*  P  = (float*)(PQ + (size_t)Bz*HWz*Cz);

    hipLaunchKernelGGL(k_pre,  dim3(276),  dim3(256), 0, stream,
                       scores, bbox, pp, dec, out, LT, RB, PQ);
    hipLaunchKernelGGL(k_main, dim3(1024), dim3(256), 0, stream,
                       (const float4*)LT, (const float4*)RB, PQ, pp, P);
    hipLaunchKernelGGL(k_red,  dim3(160),  dim3(256), 0, stream, P, out);
}